// Round 11
// baseline (443.229 us; speedup 1.0000x reference)
//
#include <hip/hip_runtime.h>

// out = (((x + 2) * 3 - 5) / 4)^2 == ((3x + 1) * 0.25)^2, elementwise fp32.
// 8192*8192 = 67108864 elements -> 256 MiB in + 256 MiB out = 537 MB HBM traffic.
// Pure streaming, zero reuse: roofline ~85 us at 6.3 TB/s achievable.
//
// Design (vs prior-session flat kernel, 410.8 us ~= 1.3 TB/s):
//  1. Grid-stride loop, grid capped at 2048 blocks (256 CU x 8 blocks/CU).
//     Persistent waves keep loads continuously in flight instead of one-shot
//     waves that issue a single load/store pair and retire.
//  2. Nontemporal loads/stores (`nt`): 512 MiB streamed with zero reuse would
//     otherwise thrash the 256 MiB L3 / 32 MiB L2.
//  3. 4-way unroll: four independent 16B loads in flight per loop trip per
//     wave (memory-level parallelism vs ~900-cycle HBM latency). Unroll
//     slices are offset by the full grid stride so coalescing is preserved.

typedef float f4 __attribute__((ext_vector_type(4)));

__device__ __forceinline__ f4 ew_op(f4 v) {
    // r = (3x + 1) * 0.25; out = r*r  (fp-contract folds mul+add to v_fma)
    f4 r = (v * 3.0f + 1.0f) * 0.25f;
    return r * r;
}

__global__ __launch_bounds__(256) void ew_kernel(const f4* __restrict__ in,
                                                 f4* __restrict__ out,
                                                 int n4) {
    int T = gridDim.x * blockDim.x;
    int i = blockIdx.x * blockDim.x + threadIdx.x;
    // 4-way unrolled main loop: all four loads issued before any store.
    for (; i + 3 * T < n4; i += 4 * T) {
        f4 v0 = __builtin_nontemporal_load(in + i);
        f4 v1 = __builtin_nontemporal_load(in + i + T);
        f4 v2 = __builtin_nontemporal_load(in + i + 2 * T);
        f4 v3 = __builtin_nontemporal_load(in + i + 3 * T);
        __builtin_nontemporal_store(ew_op(v0), out + i);
        __builtin_nontemporal_store(ew_op(v1), out + i + T);
        __builtin_nontemporal_store(ew_op(v2), out + i + 2 * T);
        __builtin_nontemporal_store(ew_op(v3), out + i + 3 * T);
    }
    // Cleanup: remaining grid-stride iterations.
    for (; i < n4; i += T) {
        f4 v = __builtin_nontemporal_load(in + i);
        __builtin_nontemporal_store(ew_op(v), out + i);
    }
}

// Scalar tail for generality (n % 4 == 0 for 8192^2, so normally not launched).
__global__ void ew_tail(const float* __restrict__ in, float* __restrict__ out,
                        int start, int n) {
    int i = start + blockIdx.x * blockDim.x + threadIdx.x;
    if (i < n) {
        float r = fmaf(3.0f, in[i], 1.0f) * 0.25f;
        out[i] = r * r;
    }
}

extern "C" void kernel_launch(void* const* d_in, const int* in_sizes, int n_in,
                              void* d_out, int out_size, void* d_ws, size_t ws_size,
                              hipStream_t stream) {
    const float* in = (const float*)d_in[0];
    float* out = (float*)d_out;
    int n = in_sizes[0];

    int n4 = n / 4;
    if (n4 > 0) {
        const int threads = 256;
        int blocks = (n4 + threads - 1) / threads;
        const int max_blocks = 2048;  // 256 CUs x 8 blocks/CU, grid-stride the rest
        if (blocks > max_blocks) blocks = max_blocks;
        ew_kernel<<<blocks, threads, 0, stream>>>((const f4*)in, (f4*)out, n4);
    }
    int rem = n - n4 * 4;
    if (rem > 0) {
        ew_tail<<<1, 64, 0, stream>>>(in, out, n4 * 4, n);
    }
}